// Round 11
// baseline (321.308 us; speedup 1.0000x reference)
//
#include <hip/hip_runtime.h>
#include <hip/hip_bf16.h>

// GMM log-likelihood, N=65536, K=32, F=128.
// Convoy-free structure: wave wid owns g-quarter wid (32 g) x all 128 n of
// the block -> 8 ds_read_b128 feed 32 MFMAs (1:4). Each wave STAGES THE SAME
// QUARTER IT READS, so load-completion is wave-private: vmcnt(0) sits at the
// top of the next comp (own loads, issued a full comp earlier -> ~free) and
// the per-comp barrier only publishes the 4-way partial exchange red[ph][n][4]
// -- no block-wide drain. LSE(k-1) deferred between comp k's MFMA groups.
// v-trick mean fold; correction folded into owner wave's partial pre-red.
// Register plan ~233/256 at 2 blocks/CU: xf[4][8]=128, fr[8]=32, acc sliced
// 2x32, xv=16 (squares of tiles 0,1 run between the MFMA groups).

#define NPTS 65536
#define KC 32
#define FD 128
#define SLABB 32768  // 4 q * 8 s * 64 lanes * 16 B per component

typedef __attribute__((ext_vector_type(8))) short short8;
typedef __attribute__((ext_vector_type(8))) unsigned short ushort8;
typedef __attribute__((ext_vector_type(16))) float f32x16;

#define MFMA(A, B, C) __builtin_amdgcn_mfma_f32_32x32x16_bf16((A), (B), (C), 0, 0, 0)

static __device__ __forceinline__ unsigned short f2bf(float f) {
  unsigned int u = __float_as_uint(f);
  u += 0x7FFFu + ((u >> 16) & 1u);  // RNE
  return (unsigned short)(u >> 16);
}

static __device__ __forceinline__ void gll(const unsigned char* g, unsigned char* l) {
  __builtin_amdgcn_global_load_lds((const __attribute__((address_space(1))) void*)g,
                                   (__attribute__((address_space(3))) void*)l, 16, 0, 0);
}

// --- prep12: fused. smp[g] = mu_k @ P_k[:,g]; v[k][f] = P_k[f,:] @ smp;
//     ck3[k] = log w + logdet - 0.5*(F*log2pi + sum_g smp^2) ---
__global__ void prep12(const float* __restrict__ means, const float* __restrict__ P,
                       const float* __restrict__ w, float* __restrict__ v,
                       float* __restrict__ ck3) {
  int k = blockIdx.x, g = threadIdx.x;  // 32 x 128
  const float* Pk = P + k * FD * FD;
  float acc = 0.f;
  for (int f = 0; f < FD; ++f) acc = fmaf(means[k * FD + f], Pk[f * FD + g], acc);
  __shared__ float smp[FD], r1[FD], r2[FD];
  smp[g] = acc;
  r1[g] = logf(Pk[g * FD + g]);
  r2[g] = acc * acc;
  __syncthreads();
  const float* Pr = Pk + g * FD;
  float a2 = 0.f;
  for (int j = 0; j < FD; ++j) a2 = fmaf(Pr[j], smp[j], a2);
  v[k * FD + g] = a2;
  for (int off = 64; off; off >>= 1) {
    if (g < off) { r1[g] += r1[g + off]; r2[g] += r2[g + off]; }
    __syncthreads();
  }
  if (g == 0)
    ck3[k] = logf(w[k]) + r1[0] - 0.5f * ((float)FD * 1.8378770664093453f + r2[0]);
}

// --- prep3: xv mini-slab (8 KB): A'[row k][f] = v[k][f], frag-major ---
__global__ void prep3(const float* __restrict__ v, unsigned char* __restrict__ Ximg) {
  int id = blockIdx.x * 256 + threadIdx.x;  // 0..511 chunks
  int l = id & 63, s = id >> 6;
  int r = l & 31, f0 = 16 * s + 8 * (l >> 5);
  ushort8 o;
#pragma unroll
  for (int j = 0; j < 8; ++j) o[j] = f2bf(v[r * FD + f0 + j]);
  *(ushort8*)(Ximg + (size_t)id * 16) = o;
}

// --- prep4: frag-major bf16 A image. chunk id -> (k,q,s,lane). ---
__global__ void prep4(const float* __restrict__ P, unsigned char* __restrict__ Aimg) {
  int id = blockIdx.x * 256 + threadIdx.x;  // 0..65535
  int l = id & 63;
  int s = (id >> 6) & 7;
  int q = (id >> 9) & 3;
  int k = id >> 11;
  int g = q * 32 + (l & 31);
  int f0 = 16 * s + 8 * (l >> 5);
  ushort8 o;
#pragma unroll
  for (int j = 0; j < 8; ++j) o[j] = f2bf(P[k * 16384 + (f0 + j) * 128 + g]);
  *(ushort8*)(Aimg + (size_t)id * 16) = o;
}

// --- main ---
__global__ __launch_bounds__(256, 2) void gmm_main(const float* __restrict__ x,
                                                   const unsigned char* __restrict__ Aimg,
                                                   const unsigned char* __restrict__ Ximg,
                                                   const float* __restrict__ ck3,
                                                   float* __restrict__ out) {
  __shared__ __align__(16) unsigned char abuf[2 * SLABB];  // 64 KB
  __shared__ __align__(16) float red[2][128][4];           // [ph][n][q]
  __shared__ float ck[KC];
  const int tid = threadIdx.x;
  const int wid = tid >> 6;   // g-quarter this wave owns, stages, and reads
  const int lane = tid & 63;
  const int half = lane >> 5;
  const int ln = lane & 31;
  const int nbase = blockIdx.x * 128;

  if (tid < KC) ck[tid] = ck3[tid];

  // prologue staging: Ximg (8 KB) -> buf1[0:8K]; slab0 quarter wid -> buf0
  {
    const unsigned char* gx = Ximg + wid * 2048 + lane * 16;
    unsigned char* lx = abuf + SLABB + wid * 2048;
    gll(gx, lx);
    gll(gx + 1024, lx + 1024);
    const unsigned char* gs = Aimg + wid * 8192 + lane * 16;
    unsigned char* ls = abuf + wid * 8192;
#pragma unroll
    for (int i = 0; i < 8; ++i) gll(gs + i * 1024, ls + i * 1024);
  }

  // B fragments: ALL 4 n-tiles of this block (128 x-rows) in registers.
  // xf[t][s][j] = x[nbase + t*32 + ln][16s + 8*half + j]   (128 VGPR)
  short8 xf[4][8];
#pragma unroll
  for (int t = 0; t < 4; ++t) {
    const float* xr = x + (size_t)(nbase + t * 32 + ln) * FD + 8 * half;
#pragma unroll
    for (int s = 0; s < 8; ++s) {
      const float4 a = *(const float4*)(xr + 16 * s);
      const float4 b = *(const float4*)(xr + 16 * s + 4);
      short8 f;
      f[0] = (short)f2bf(a.x); f[1] = (short)f2bf(a.y);
      f[2] = (short)f2bf(a.z); f[3] = (short)f2bf(a.w);
      f[4] = (short)f2bf(b.x); f[5] = (short)f2bf(b.y);
      f[6] = (short)f2bf(b.z); f[7] = (short)f2bf(b.w);
      xf[t][s] = f;
    }
  }

  asm volatile("s_waitcnt vmcnt(0)" ::: "memory");
  __syncthreads();  // Ximg + slab0 resident (cross-wave Ximg needs this one)

  // xv mini-GEMM for n-tile wid: rows k = (i&3)+8*(i>>2)+4*half, col = ln
  f32x16 xv;
#pragma unroll
  for (int i = 0; i < 16; ++i) xv[i] = 0.f;
  {
    const unsigned char* xb = abuf + SLABB + lane * 16;
#pragma unroll
    for (int s = 0; s < 8; ++s) {
      const short8 fx = *(const short8*)(xb + s * 1024);
      xv = MFMA(fx, xf[wid][s], xv);
    }
  }
  __syncthreads();  // xv reads done -> buf1's Ximg region reusable by comp 0

  float m = -__builtin_inff(), ssum = 0.f, sc = 0.f;

  for (int k = 0; k < KC; ++k) {
    const int RB = (k & 1) * SLABB;
    const int WB = SLABB - RB;
    const int ph = k & 1;
    // own quarter's stage loads (issued one comp ago) -> ~free wait
    asm volatile("s_waitcnt vmcnt(0)" ::: "memory");
    const unsigned char* rb = abuf + RB + wid * 8192 + lane * 16;
    short8 fr[8];
#pragma unroll
    for (int s = 0; s < 8; ++s) fr[s] = *(const short8*)(rb + s * 1024);
    if (k + 1 < KC) {  // stage own quarter of slab k+1 (wave-private!)
      const unsigned char* gs = Aimg + (size_t)(k + 1) * SLABB + wid * 8192 + lane * 16;
      unsigned char* ls = abuf + WB + wid * 8192;
#pragma unroll
      for (int i = 0; i < 8; ++i) gll(gs + i * 1024, ls + i * 1024);
    }
    // MFMA group 1: n-tiles 0,1
    f32x16 a0, a1;
#pragma unroll
    for (int i = 0; i < 16; ++i) { a0[i] = 0.f; a1[i] = 0.f; }
    __builtin_amdgcn_s_setprio(1);
#pragma unroll
    for (int s = 0; s < 8; ++s) {
      a0 = MFMA(fr[s], xf[0][s], a0);
      a1 = MFMA(fr[s], xf[1][s], a1);
    }
    __builtin_amdgcn_s_setprio(0);
    // deferred LSE of comp k-1 (register-only; overlaps in-flight MFMAs)
    if (k > 0) {
      float vv = ck[k - 1] - 0.5f * sc;
      float nm = fmaxf(m, vv);
      ssum = ssum * __expf(m - nm) + __expf(vv - nm);
      m = nm;
    }
    // squares of tiles 0,1 (frees a0,a1 before group 2 -> caps live accs)
    float p0 = 0.f, p1 = 0.f;
#pragma unroll
    for (int i = 0; i < 16; ++i) {
      p0 = fmaf(a0[i], a0[i], p0);
      p1 = fmaf(a1[i], a1[i], p1);
    }
    // MFMA group 2: n-tiles 2,3
    f32x16 b0, b1;
#pragma unroll
    for (int i = 0; i < 16; ++i) { b0[i] = 0.f; b1[i] = 0.f; }
    __builtin_amdgcn_s_setprio(1);
#pragma unroll
    for (int s = 0; s < 8; ++s) {
      b0 = MFMA(fr[s], xf[2][s], b0);
      b1 = MFMA(fr[s], xf[3][s], b1);
    }
    __builtin_amdgcn_s_setprio(0);
    p0 += __shfl_xor(p0, 32, 64);  // full 32-g quarter sums
    p1 += __shfl_xor(p1, 32, 64);
    float p2 = 0.f, p3 = 0.f;
#pragma unroll
    for (int i = 0; i < 16; ++i) {
      p2 = fmaf(b0[i], b0[i], p2);
      p3 = fmaf(b1[i], b1[i], p3);
    }
    p2 += __shfl_xor(p2, 32, 64);
    p3 += __shfl_xor(p3, 32, 64);
    // v-trick correction: owner wave folds -2*xv[n,k] into its tile-wid partial
    {
      const int owner = (k >> 2) & 1;
      const int idx = (k & 3) | ((k >> 3) << 2);
      float tx = (half == owner) ? xv[idx] : 0.f;
      tx += __shfl_xor(tx, 32, 64);
      const float corr = -2.f * tx;
      if (wid == 0) p0 += corr;
      else if (wid == 1) p1 += corr;
      else if (wid == 2) p2 += corr;
      else p3 += corr;
    }
    // publish partials: red[ph][t*32+ln][wid]; halves split the 4 writes
    if (half == 0) {
      red[ph][ln][wid] = p0;
      red[ph][32 + ln][wid] = p1;
    } else {
      red[ph][64 + ln][wid] = p2;
      red[ph][96 + ln][wid] = p3;
    }
    __syncthreads();  // the ONLY block sync per comp: publishes red[ph]
    if (tid < 128) {
      const float4 r = *(const float4*)red[ph][tid];
      sc = (r.x + r.y) + (r.z + r.w);  // full 128-g Mahalanobis (+corr)
    }
  }

  if (tid < 128) {  // final LSE for comp KC-1 and output
    float vv = ck[KC - 1] - 0.5f * sc;
    float nm = fmaxf(m, vv);
    ssum = ssum * __expf(m - nm) + __expf(vv - nm);
    m = nm;
    out[nbase + tid] = m + logf(ssum);
  }
}

extern "C" void kernel_launch(void* const* d_in, const int* in_sizes, int n_in,
                              void* d_out, int out_size, void* d_ws, size_t ws_size,
                              hipStream_t stream) {
  const float* x = (const float*)d_in[0];
  const float* means = (const float*)d_in[1];
  const float* P = (const float*)d_in[2];
  const float* w = (const float*)d_in[3];
  float* out = (float*)d_out;

  unsigned char* ws = (unsigned char*)d_ws;
  unsigned char* Aimg = ws;                       // 1048576 B
  unsigned char* Ximg = ws + 1048576;             // 8192 B
  float* v = (float*)(ws + 1048576 + 8192);       // 16384 B
  float* ck3 = (float*)(ws + 1048576 + 24576);    // 128 B

  prep12<<<32, 128, 0, stream>>>(means, P, w, v, ck3);
  prep3<<<2, 256, 0, stream>>>(v, Ximg);
  prep4<<<256, 256, 0, stream>>>(P, Aimg);
  gmm_main<<<NPTS / 128, 256, 0, stream>>>(x, Aimg, Ximg, ck3, out);
}

// Round 12
// 78.187 us; speedup vs baseline: 4.1095x; 4.1095x over previous
//
#include <hip/hip_runtime.h>
#include <hip/hip_bf16.h>

// GMM log-likelihood, N=65536, K=32, F=128.
// 512-thread block (8 waves = 2/SIMD), 1 block/CU, grid 256. Wave (gh,nq)
// owns 64 g-rows (g-half gh) x 64 n-rows (quarter nq): 16 ds_read_b128 ->
// 32 MFMAs/comp (1:2), R10's proven ~200-reg plan (xf[2][8]=64, one fr[8]=32,
// acc 64, xv/zc 32). T3/T4: 3-slab LDS ring with 2-comp-deep prefetch --
// comp k stages slab k+2 and ends with s_waitcnt vmcnt(4) (drains slab k+1's
// loads issued a full comp earlier ~ free; never the just-issued ones) then
// the barrier publishes. No vmcnt(0) convoy in the loop. v-trick mean fold;
// pairwise xch combine (partner wid^1), double-phased. 1 barrier/comp.

#define NPTS 65536
#define KC 32
#define FD 128
#define SLABB 32768  // 4 q * 8 s * 64 lanes * 16 B per component

typedef __attribute__((ext_vector_type(8))) short short8;
typedef __attribute__((ext_vector_type(8))) unsigned short ushort8;
typedef __attribute__((ext_vector_type(16))) float f32x16;

#define MFMA(A, B, C) __builtin_amdgcn_mfma_f32_32x32x16_bf16((A), (B), (C), 0, 0, 0)

static __device__ __forceinline__ unsigned short f2bf(float f) {
  unsigned int u = __float_as_uint(f);
  u += 0x7FFFu + ((u >> 16) & 1u);  // RNE
  return (unsigned short)(u >> 16);
}

static __device__ __forceinline__ void gll(const unsigned char* g, unsigned char* l) {
  __builtin_amdgcn_global_load_lds((const __attribute__((address_space(1))) void*)g,
                                   (__attribute__((address_space(3))) void*)l, 16, 0, 0);
}

// --- prep12: fused. smp[g] = mu_k @ P_k[:,g]; v[k][f] = P_k[f,:] @ smp;
//     ck3[k] = log w + logdet - 0.5*(F*log2pi + sum_g smp^2) ---
__global__ void prep12(const float* __restrict__ means, const float* __restrict__ P,
                       const float* __restrict__ w, float* __restrict__ v,
                       float* __restrict__ ck3) {
  int k = blockIdx.x, g = threadIdx.x;  // 32 x 128
  const float* Pk = P + k * FD * FD;
  float acc = 0.f;
  for (int f = 0; f < FD; ++f) acc = fmaf(means[k * FD + f], Pk[f * FD + g], acc);
  __shared__ float smp[FD], r1[FD], r2[FD];
  smp[g] = acc;
  r1[g] = logf(Pk[g * FD + g]);
  r2[g] = acc * acc;
  __syncthreads();
  const float* Pr = Pk + g * FD;
  float a2 = 0.f;
  for (int j = 0; j < FD; ++j) a2 = fmaf(Pr[j], smp[j], a2);
  v[k * FD + g] = a2;
  for (int off = 64; off; off >>= 1) {
    if (g < off) { r1[g] += r1[g + off]; r2[g] += r2[g + off]; }
    __syncthreads();
  }
  if (g == 0)
    ck3[k] = logf(w[k]) + r1[0] - 0.5f * ((float)FD * 1.8378770664093453f + r2[0]);
}

// --- prep3: xv mini-slab (8 KB): A'[row k][f] = v[k][f], frag-major ---
__global__ void prep3(const float* __restrict__ v, unsigned char* __restrict__ Ximg) {
  int id = blockIdx.x * 256 + threadIdx.x;  // 0..511 chunks
  int l = id & 63, s = id >> 6;
  int r = l & 31, f0 = 16 * s + 8 * (l >> 5);
  ushort8 o;
#pragma unroll
  for (int j = 0; j < 8; ++j) o[j] = f2bf(v[r * FD + f0 + j]);
  *(ushort8*)(Ximg + (size_t)id * 16) = o;
}

// --- prep4: frag-major bf16 A image. chunk id -> (k,q,s,lane). ---
__global__ void prep4(const float* __restrict__ P, unsigned char* __restrict__ Aimg) {
  int id = blockIdx.x * 256 + threadIdx.x;  // 0..65535
  int l = id & 63;
  int s = (id >> 6) & 7;
  int q = (id >> 9) & 3;
  int k = id >> 11;
  int g = q * 32 + (l & 31);
  int f0 = 16 * s + 8 * (l >> 5);
  ushort8 o;
#pragma unroll
  for (int j = 0; j < 8; ++j) o[j] = f2bf(P[k * 16384 + (f0 + j) * 128 + g]);
  *(ushort8*)(Aimg + (size_t)id * 16) = o;
}

// --- main ---
__global__ __launch_bounds__(512, 2) void gmm_main(const float* __restrict__ x,
                                                   const unsigned char* __restrict__ Aimg,
                                                   const unsigned char* __restrict__ Ximg,
                                                   const float* __restrict__ ck3,
                                                   float* __restrict__ out) {
  __shared__ __align__(16) unsigned char abuf[3 * SLABB];  // 96 KB ring
  __shared__ __align__(16) float xch[2][8][32];
  __shared__ float ck[KC];
  const int tid = threadIdx.x;
  const int wid = tid >> 6;   // 0..7
  const int lane = tid & 63;
  const int half = lane >> 5;
  const int ln = lane & 31;
  const int gh = wid & 1;     // g-half this wave owns (g-tiles gh*2, gh*2+1)
  const int nq = wid >> 1;    // n-quarter this wave owns (64 x-rows)
  const int nbase = blockIdx.x * 256;

  if (tid < KC) ck[tid] = ck3[tid];

  // prologue staging: slab0 -> ring0, slab1 -> ring1, Ximg -> ring2.
  // each wave stages 4 KB per slab (4 gll) and 1 KB of Ximg (1 gll).
  {
    const unsigned char* g0 = Aimg + wid * 4096 + lane * 16;
    unsigned char* l0 = abuf + wid * 4096;
#pragma unroll
    for (int i = 0; i < 4; ++i) gll(g0 + i * 1024, l0 + i * 1024);
    const unsigned char* g1 = Aimg + SLABB + wid * 4096 + lane * 16;
    unsigned char* l1 = abuf + SLABB + wid * 4096;
#pragma unroll
    for (int i = 0; i < 4; ++i) gll(g1 + i * 1024, l1 + i * 1024);
    gll(Ximg + wid * 1024 + lane * 16, abuf + 2 * SLABB + wid * 1024);
  }

  // B fragments: this wave's 64 x-rows (2 n-tiles), resident all kernel.
  // xf[t][s][j] = x[nbase + nq*64 + t*32 + ln][16s + 8*half + j]  (64 VGPR)
  short8 xf[2][8];
#pragma unroll
  for (int t = 0; t < 2; ++t) {
    const float* xr = x + (size_t)(nbase + nq * 64 + t * 32 + ln) * FD + 8 * half;
#pragma unroll
    for (int s = 0; s < 8; ++s) {
      const float4 a = *(const float4*)(xr + 16 * s);
      const float4 b = *(const float4*)(xr + 16 * s + 4);
      short8 f;
      f[0] = (short)f2bf(a.x); f[1] = (short)f2bf(a.y);
      f[2] = (short)f2bf(a.z); f[3] = (short)f2bf(a.w);
      f[4] = (short)f2bf(b.x); f[5] = (short)f2bf(b.y);
      f[6] = (short)f2bf(b.z); f[7] = (short)f2bf(b.w);
      xf[t][s] = f;
    }
  }

  f32x16 zc;  // persistent zero C-operand
#pragma unroll
  for (int i = 0; i < 16; ++i) zc[i] = 0.f;

  asm volatile("s_waitcnt vmcnt(0)" ::: "memory");
  __syncthreads();  // slab0, slab1, Ximg all resident

  // xv[n,k] mini-GEMM for the n-tile this wave finalizes (t == gh):
  // row k = (i&3)+8*(i>>2)+4*half, col n = nbase + nq*64 + gh*32 + ln
  f32x16 xv;
  {
    const unsigned char* xb = abuf + 2 * SLABB + lane * 16;
    {
      const short8 fx = *(const short8*)xb;
      xv = MFMA(fx, gh ? xf[1][0] : xf[0][0], zc);
    }
#pragma unroll
    for (int s = 1; s < 8; ++s) {
      const short8 fx = *(const short8*)(xb + s * 1024);
      xv = MFMA(fx, gh ? xf[1][s] : xf[0][s], xv);
    }
  }
  __syncthreads();  // xv consumed -> ring2 reusable for slab2 (staged at k=0)

  float m = -__builtin_inff(), ssum = 0.f;
  int r0 = 0, r1 = SLABB, r2 = 2 * SLABB;  // ring: read r0, stage k+2 -> r2

  for (int k = 0; k < KC; ++k) {
    const int ph = k & 1;
    // ds_reads for g-tile gh*2 (single fr bank, reused)
    const unsigned char* rb = abuf + r0 + gh * 16384 + lane * 16;
    short8 fr[8];
#pragma unroll
    for (int s = 0; s < 8; ++s) fr[s] = *(const short8*)(rb + s * 1024);
    if (k + 2 < KC) {  // stage slab k+2 into ring r2 (4 gll per wave)
      const unsigned char* gs = Aimg + (size_t)(k + 2) * SLABB + wid * 4096 + lane * 16;
      unsigned char* ls = abuf + r2 + wid * 4096;
#pragma unroll
      for (int i = 0; i < 4; ++i) gll(gs + i * 1024, ls + i * 1024);
    }
    __builtin_amdgcn_s_setprio(1);
    f32x16 a00 = MFMA(fr[0], xf[0][0], zc);
    f32x16 a01 = MFMA(fr[0], xf[1][0], zc);
#pragma unroll
    for (int s = 1; s < 8; ++s) {
      a00 = MFMA(fr[s], xf[0][s], a00);
      a01 = MFMA(fr[s], xf[1][s], a01);
    }
    // reload fr bank for g-tile gh*2+1
#pragma unroll
    for (int s = 0; s < 8; ++s) fr[s] = *(const short8*)(rb + 8192 + s * 1024);
    f32x16 a10 = MFMA(fr[0], xf[0][0], zc);
    f32x16 a11 = MFMA(fr[0], xf[1][0], zc);
#pragma unroll
    for (int s = 1; s < 8; ++s) {
      a10 = MFMA(fr[s], xf[0][s], a10);
      a11 = MFMA(fr[s], xf[1][s], a11);
    }
    __builtin_amdgcn_s_setprio(0);
    // epilogue: per-n-tile squares over this wave's 64 g
    float q0a = 0.f, q0b = 0.f, q1a = 0.f, q1b = 0.f;
#pragma unroll
    for (int i = 0; i < 16; ++i) {
      q0a = fmaf(a00[i], a00[i], q0a);
      q0b = fmaf(a10[i], a10[i], q0b);
      q1a = fmaf(a01[i], a01[i], q1a);
      q1b = fmaf(a11[i], a11[i], q1b);
    }
    float q0 = q0a + q0b, q1 = q1a + q1b;
    q0 += __shfl_xor(q0, 32, 64);  // both halves hold full 64-g partials
    q1 += __shfl_xor(q1, 32, 64);
    float sown = gh ? q1 : q0;  // n-tile this wave finalizes (t == gh)
    float soth = gh ? q0 : q1;  // n-tile the partner (wid^1) finalizes
    if (half == 0) xch[ph][wid ^ 1][ln] = soth;
    // counted wait: drain slab k+1's own loads (issued one comp ago, ~free);
    // leave the 4 just-issued slab-k+2 loads in flight across the barrier.
    if (k + 2 < KC) asm volatile("s_waitcnt vmcnt(4)" ::: "memory");
    else            asm volatile("s_waitcnt vmcnt(0)" ::: "memory");
    __syncthreads();  // publishes slab k+1 + xch (one barrier/comp)
    float sfull = sown + xch[ph][wid][ln];
    // -2 * x.v_k, made half-uniform with one shfl
    const int owner = (k >> 2) & 1;
    const int idx = (k & 3) | ((k >> 3) << 2);
    float tx = (half == owner) ? xv[idx] : 0.f;
    tx += __shfl_xor(tx, 32, 64);
    sfull = fmaf(-2.f, tx, sfull);
    float vv = ck[k] - 0.5f * sfull;
    float nm = fmaxf(m, vv);
    ssum = ssum * __expf(m - nm) + __expf(vv - nm);
    m = nm;
    const int rt = r0; r0 = r1; r1 = r2; r2 = rt;  // rotate ring
  }

  if (half == 0) out[nbase + nq * 64 + gh * 32 + ln] = m + logf(ssum);
}

extern "C" void kernel_launch(void* const* d_in, const int* in_sizes, int n_in,
                              void* d_out, int out_size, void* d_ws, size_t ws_size,
                              hipStream_t stream) {
  const float* x = (const float*)d_in[0];
  const float* means = (const float*)d_in[1];
  const float* P = (const float*)d_in[2];
  const float* w = (const float*)d_in[3];
  float* out = (float*)d_out;

  unsigned char* ws = (unsigned char*)d_ws;
  unsigned char* Aimg = ws;                       // 1048576 B
  unsigned char* Ximg = ws + 1048576;             // 8192 B
  float* v = (float*)(ws + 1048576 + 8192);       // 16384 B
  float* ck3 = (float*)(ws + 1048576 + 24576);    // 128 B

  prep12<<<32, 128, 0, stream>>>(means, P, w, v, ck3);
  prep3<<<2, 256, 0, stream>>>(v, Ximg);
  prep4<<<256, 256, 0, stream>>>(P, Aimg);
  gmm_main<<<NPTS / 256, 512, 0, stream>>>(x, Aimg, Ximg, ck3, out);
}